// Round 7
// baseline (292.887 us; speedup 1.0000x reference)
//
#include <hip/hip_runtime.h>
#include <hip/hip_bf16.h>

#define B_   8
#define LQ   3136
#define LK   784
#define C_   192
#define NCH  49
#define EPSV 1e-5f
#define LOG2E 1.4426950408889634f

using f32x4 = __attribute__((ext_vector_type(4))) float;
using s16x8 = __attribute__((ext_vector_type(8))) short;
using s16x4 = __attribute__((ext_vector_type(4))) short;
using us4   = __attribute__((ext_vector_type(4))) unsigned short;

#if __has_builtin(__builtin_amdgcn_mfma_f32_16x16x16bf16_1k)
#define HAVE_MFMA16 1
#else
#define HAVE_MFMA16 0
#endif

static __device__ __forceinline__ unsigned short f2bf(float x) {
  return __builtin_bit_cast(unsigned short, __float2bfloat16(x));
}

// ---------------- merged prep: dw_s1 (blocks 0..4703) + dw_s2 K&V (4704..5879) + wprep (5880..6455) ----
__global__ __launch_bounds__(256) void prep_kernel(
    const float* __restrict__ xq, const float* __restrict__ xkv,
    const float* __restrict__ qdw_w, const float* __restrict__ qsc, const float* __restrict__ qbi,
    const float* __restrict__ qme,  const float* __restrict__ qva,
    const float* __restrict__ kdw_w, const float* __restrict__ ksc, const float* __restrict__ kbi,
    const float* __restrict__ kme,  const float* __restrict__ kva,
    const float* __restrict__ vdw_w, const float* __restrict__ vsc, const float* __restrict__ vbi,
    const float* __restrict__ vme,  const float* __restrict__ vva,
    const float* __restrict__ w0, const float* __restrict__ w1,
    const float* __restrict__ w2, const float* __restrict__ w3,
    short* __restrict__ qy, short* __restrict__ ky, short* __restrict__ vy,
    short* __restrict__ Wt)
{
  const int bid = blockIdx.x;
  if (bid < 4704) {
    int g = bid * 256 + threadIdx.x;                // B*3136*48 exact
    int c4 = (g % 48) * 4; int t = g / 48;
    int xx = t % 56, yy = (t / 56) % 56, b = t / 3136;
    float4 s = {0.f, 0.f, 0.f, 0.f};
#pragma unroll
    for (int dy = 0; dy < 3; ++dy) {
      int iy = yy + dy - 1;
      if (iy < 0 || iy >= 56) continue;
#pragma unroll
      for (int dx = 0; dx < 3; ++dx) {
        int ix = xx + dx - 1;
        if (ix < 0 || ix >= 56) continue;
        float4 xv = *(const float4*)&xq[((size_t)((b * 56 + iy) * 56 + ix)) * C_ + c4];
        float4 wv = *(const float4*)&qdw_w[(dy * 3 + dx) * C_ + c4];
        s.x += xv.x * wv.x; s.y += xv.y * wv.y; s.z += xv.z * wv.z; s.w += xv.w * wv.w;
      }
    }
    float4 scv = *(const float4*)&qsc[c4]; float4 biv = *(const float4*)&qbi[c4];
    float4 mev = *(const float4*)&qme[c4]; float4 vav = *(const float4*)&qva[c4];
    us4 o;
    o[0] = f2bf((s.x - mev.x) * (scv.x * rsqrtf(vav.x + EPSV)) + biv.x);
    o[1] = f2bf((s.y - mev.y) * (scv.y * rsqrtf(vav.y + EPSV)) + biv.y);
    o[2] = f2bf((s.z - mev.z) * (scv.z * rsqrtf(vav.z + EPSV)) + biv.z);
    o[3] = f2bf((s.w - mev.w) * (scv.w * rsqrtf(vav.w + EPSV)) + biv.w);
    *(us4*)&qy[(size_t)t * C_ + c4] = o;
  } else if (bid < 5880) {
    int g = (bid - 4704) * 256 + threadIdx.x;       // B*784*48 exact
    int c4 = (g % 48) * 4; int t = g / 48;
    int xo = t % 28, yo = (t / 28) % 28, b = t / 784;
    float4 sk = {0.f, 0.f, 0.f, 0.f}, sv = {0.f, 0.f, 0.f, 0.f};
#pragma unroll
    for (int dy = 0; dy < 3; ++dy) {
      int iy = yo * 2 + dy;        // SAME stride-2: pad_lo=0, pad_hi=1
      if (iy >= 56) continue;
#pragma unroll
      for (int dx = 0; dx < 3; ++dx) {
        int ix = xo * 2 + dx;
        if (ix >= 56) continue;
        float4 xv = *(const float4*)&xkv[((size_t)((b * 56 + iy) * 56 + ix)) * C_ + c4];
        float4 kw = *(const float4*)&kdw_w[(dy * 3 + dx) * C_ + c4];
        float4 vw = *(const float4*)&vdw_w[(dy * 3 + dx) * C_ + c4];
        sk.x += xv.x * kw.x; sk.y += xv.y * kw.y; sk.z += xv.z * kw.z; sk.w += xv.w * kw.w;
        sv.x += xv.x * vw.x; sv.y += xv.y * vw.y; sv.z += xv.z * vw.z; sv.w += xv.w * vw.w;
      }
    }
    us4 ko, vo;
#pragma unroll
    for (int j = 0; j < 4; ++j) {
      int c = c4 + j;
      float skj = (j == 0) ? sk.x : (j == 1) ? sk.y : (j == 2) ? sk.z : sk.w;
      float svj = (j == 0) ? sv.x : (j == 1) ? sv.y : (j == 2) ? sv.z : sv.w;
      ko[j] = f2bf((skj - kme[c]) * (ksc[c] * rsqrtf(kva[c] + EPSV)) + kbi[c]);
      vo[j] = f2bf((svj - vme[c]) * (vsc[c] * rsqrtf(vva[c] + EPSV)) + vbi[c]);
    }
    *(us4*)&ky[(size_t)t * C_ + c4] = ko;
    *(us4*)&vy[(size_t)t * C_ + c4] = vo;
  } else {
    int i = (bid - 5880) * 256 + threadIdx.x;       // 4*36864 exact
    int m = i / 36864, r = i % 36864;
    int k = r / 192, n = r % 192;
    const float* W = (m == 0) ? w0 : (m == 1) ? w1 : (m == 2) ? w2 : w3;
    Wt[m * 36864 + n * 192 + k] = (short)f2bf(W[r]);
  }
}

// ---------------- bf16 MFMA GEMM core: Y[64 x 192] = X[64 x 192] * Wt^T ----------------
// mode 0: Y bf16 [tok][n] * scale.
// mode 1: Y bf16 lane-major tiled V^T: chunk base (bb*49+ch)*3072, short idx
//         hd*256 + lg*64 + lr*4 + j  where hd=d>>4, lr=d&15, k=lg*4+j.
__device__ __forceinline__ void gemm_core(
    const short* __restrict__ X, const short* __restrict__ Wt,
    short* __restrict__ Y, int mode, float scale, int blkrow)
{
  const int tid = threadIdx.x;
  const int w = tid >> 6, lane = tid & 63;
  const int lr = lane & 15, lg = lane >> 4;
  const int rowA = blkrow * 64 + w * 16 + lr;          // A-frag row (m = lane&15)
  const short* Xrow = X + (size_t)rowA * C_ + lg * 8;
  s16x8 af[6];
#pragma unroll
  for (int kk = 0; kk < 6; ++kk) af[kk] = *(const s16x8*)(Xrow + kk * 32);
  f32x4 acc[12] = {};
#pragma unroll
  for (int nt = 0; nt < 12; ++nt) {
    const short* wr = Wt + (size_t)(nt * 16 + lr) * C_ + lg * 8;
#pragma unroll
    for (int kk = 0; kk < 6; ++kk) {
      s16x8 bf_ = *(const s16x8*)(wr + kk * 32);
      acc[nt] = __builtin_amdgcn_mfma_f32_16x16x32_bf16(af[kk], bf_, acc[nt], 0, 0, 0);
    }
  }
  const int tok0 = blkrow * 64 + w * 16 + lg * 4;      // D rows: (lane>>4)*4 + r
#pragma unroll
  for (int nt = 0; nt < 12; ++nt) {
    int n = nt * 16 + lr;
    if (mode == 1) {
      int bb = tok0 / LK, k0 = tok0 - bb * LK;   // tok0..tok0+3 within same chunk (k = lg*4+r)
      int ch = k0 >> 4;
      us4 pk;
#pragma unroll
      for (int r = 0; r < 4; ++r) pk[r] = f2bf(acc[nt][r] * scale);
      *(us4*)&Y[((size_t)bb * NCH + ch) * 3072 + nt * 256 + lg * 64 + lr * 4] = pk;
    } else {
#pragma unroll
      for (int r = 0; r < 4; ++r) {
        int tok = tok0 + r;
        Y[(size_t)tok * C_ + n] = (short)f2bf(acc[nt][r] * scale);
      }
    }
  }
}

// merged projection GEMMs: blocks 0..391 Q, 392..489 K, 490..587 V
__global__ __launch_bounds__(256) void proj_gemm_kernel(
    const short* __restrict__ qdwb, const short* __restrict__ kdwb, const short* __restrict__ vdwb,
    const short* __restrict__ WtQ, const short* __restrict__ WtK, const short* __restrict__ WtV,
    short* __restrict__ Qb, short* __restrict__ Kb, short* __restrict__ VTb)
{
  const int bid = blockIdx.x;
  if (bid < 392)      gemm_core(qdwb, WtQ, Qb, 0, 0.125f, bid);
  else if (bid < 490) gemm_core(kdwb, WtK, Kb, 0, 1.0f, bid - 392);
  else                gemm_core(vdwb, WtV, VTb, 1, 1.0f, bid - 490);
}

// final out-projection: Y fp32 [tok][n]
__global__ __launch_bounds__(256) void out_gemm_kernel(
    const short* __restrict__ X, const short* __restrict__ Wt, float* __restrict__ Y)
{
  const int tid = threadIdx.x;
  const int w = tid >> 6, lane = tid & 63;
  const int lr = lane & 15, lg = lane >> 4;
  const int rowA = blockIdx.x * 64 + w * 16 + lr;
  const short* Xrow = X + (size_t)rowA * C_ + lg * 8;
  s16x8 af[6];
#pragma unroll
  for (int kk = 0; kk < 6; ++kk) af[kk] = *(const s16x8*)(Xrow + kk * 32);
  f32x4 acc[12] = {};
#pragma unroll
  for (int nt = 0; nt < 12; ++nt) {
    const short* wr = Wt + (size_t)(nt * 16 + lr) * C_ + lg * 8;
#pragma unroll
    for (int kk = 0; kk < 6; ++kk) {
      s16x8 bf_ = *(const s16x8*)(wr + kk * 32);
      acc[nt] = __builtin_amdgcn_mfma_f32_16x16x32_bf16(af[kk], bf_, acc[nt], 0, 0, 0);
    }
  }
  const int tok0 = blockIdx.x * 64 + w * 16 + lg * 4;
#pragma unroll
  for (int nt = 0; nt < 12; ++nt) {
    int n = nt * 16 + lr;
#pragma unroll
    for (int r = 0; r < 4; ++r)
      Y[(size_t)(tok0 + r) * C_ + n] = acc[nt][r];
  }
}

// ---------------- fused head-mixed attention: 2 waves/block, 32q, lane-major LDS ----------------
// K LDS unit (f, lane) at byte (f*64+lane)*16  -> ds_read_b128 lane-contiguous, conflict-free.
// V LDS unit (hd, lane) at byte (hd*64+lane)*8 -> ds_read_b64  lane-contiguous, conflict-free.
// Staging writes are tid-contiguous (conflict-free); global V^T chunk is lane-major so V staging
// is a pure linear copy. XCD swizzle: 784 blocks = 8 XCDs x 98 -> each XCD serves one batch.
__global__ __launch_bounds__(128) void attn_mfma_kernel(
    const short* __restrict__ Q,   // [B][3136][192] bf16, pre-scaled 1/8
    const short* __restrict__ K,   // [B][784][192] bf16
    const short* __restrict__ VTt, // [B][49][3072] bf16 lane-major tiled
    const float* __restrict__ pre, const float* __restrict__ post,
    short* __restrict__ Ob)        // [B][3136][192] bf16
{
  __shared__ short Klds[2][3072];
  __shared__ short Vlds[2][3072];

  const int tid = threadIdx.x;
  const int lane = tid & 63, w = tid >> 6;   // w in {0,1}
  const int lr = lane & 15, lg = lane >> 4;
  const int bid0 = blockIdx.x;
  const int bid = (bid0 & 7) * 98 + (bid0 >> 3);   // bijective XCD swizzle (784 = 8*98)
  const int b = bid / 98, qt = bid % 98;
  const int q0 = qt * 32 + w * 16;

  float pm[9], po[9];
#pragma unroll
  for (int i = 0; i < 9; ++i) { pm[i] = pre[i] * LOG2E; po[i] = post[i]; }

  const short* Kg = K + (size_t)b * LK * C_;
  const short* Vg = VTt + (size_t)b * NCH * 3072;

  // K staging source offsets, lane-major: unit u = tid + t*128 -> (f=u>>6, lr_u=u&15, lg_u=(u>>4)&3)
  int kg[3];
#pragma unroll
  for (int t = 0; t < 3; ++t) {
    int u = tid + t * 128;
    int f = u >> 6;
    kg[t] = (u & 15) * C_ + (f >> 1) * 64 + (f & 1) * 32 + ((u >> 4) & 3) * 8;
  }

  // Q fragments (held for whole kernel)
  const short* Qp = Q + ((size_t)b * LQ + q0 + lr) * C_ + lg * 8;
  s16x8 qf[3][2];
#pragma unroll
  for (int h = 0; h < 3; ++h)
#pragma unroll
    for (int kk = 0; kk < 2; ++kk)
      qf[h][kk] = *(const s16x8*)(Qp + h * 64 + kk * 32);

  const f32x4 zz = {0.f, 0.f, 0.f, 0.f};

  // ================= pass 1: softmax denominators =================
  float lp0 = 0.f, lp1 = 0.f, lp2 = 0.f;
#pragma unroll
  for (int t = 0; t < 3; ++t)
    *(s16x8*)&Klds[0][(tid + t * 128) * 8] = *(const s16x8*)(Kg + kg[t]);
  __syncthreads();
  for (int c = 0; c < NCH; ++c) {
    s16x8 kr[3];
    const bool pf = (c + 1 < NCH);
    if (pf) {
      const short* g = Kg + (size_t)(c + 1) * 16 * C_;
#pragma unroll
      for (int t = 0; t < 3; ++t) kr[t] = *(const s16x8*)(g + kg[t]);
    }
    const short* kb = Klds[c & 1];
    s16x8 kf[6];
#pragma unroll
    for (int f = 0; f < 6; ++f)
      kf[f] = *(const s16x8*)&kb[(f * 64 + lane) * 8];
    f32x4 sT[3];
#pragma unroll
    for (int h = 0; h < 3; ++h) {
      sT[h] = __builtin_amdgcn_mfma_f32_16x16x32_bf16(kf[h * 2], qf[h][0], zz, 0, 0, 0);
      sT[h] = __builtin_amdgcn_mfma_f32_16x16x32_bf16(kf[h * 2 + 1], qf[h][1], sT[h], 0, 0, 0);
    }
#pragma unroll
    for (int r = 0; r < 4; ++r) {
      float s0 = sT[0][r], s1 = sT[1][r], s2 = sT[2][r];
      lp0 += exp2f(pm[0] * s0 + pm[3] * s1 + pm[6] * s2);
      lp1 += exp2f(pm[1] * s0 + pm[4] * s1 + pm[7] * s2);
      lp2 += exp2f(pm[2] * s0 + pm[5] * s1 + pm[8] * s2);
    }
    if (pf) {
      short* kd = Klds[(c + 1) & 1];
#pragma unroll
      for (int t = 0; t < 3; ++t)
        *(s16x8*)&kd[(tid + t * 128) * 8] = kr[t];
    }
    __syncthreads();
  }
  lp0 += __shfl_xor(lp0, 16); lp0 += __shfl_xor(lp0, 32);
  lp1 += __shfl_xor(lp1, 16); lp1 += __shfl_xor(lp1, 32);
  lp2 += __shfl_xor(lp2, 16); lp2 += __shfl_xor(lp2, 32);
  const float li0 = 1.0f / lp0, li1 = 1.0f / lp1, li2 = 1.0f / lp2;
  float poli[9];
#pragma unroll
  for (int h = 0; h < 3; ++h) {
    poli[h]     = po[h]     * li0;
    poli[3 + h] = po[3 + h] * li1;
    poli[6 + h] = po[6 + h] * li2;
  }

  // ================= pass 2: P and PV =================
#pragma unroll
  for (int t = 0; t < 3; ++t) {
    *(s16x8*)&Klds[0][(tid + t * 128) * 8] = *(const s16x8*)(Kg + kg[t]);
    *(s16x8*)&Vlds[0][(tid + t * 128) * 8] = *(const s16x8*)(Vg + (tid + t * 128) * 8);
  }
  __syncthreads();

  f32x4 o[3][4] = {};
  for (int c = 0; c < NCH; ++c) {
    s16x8 kr[3], vr[3];
    const bool pf = (c + 1 < NCH);
    if (pf) {
      const short* g = Kg + (size_t)(c + 1) * 16 * C_;
      const short* gv = Vg + (size_t)(c + 1) * 3072;
#pragma unroll
      for (int t = 0; t < 3; ++t) {
        kr[t] = *(const s16x8*)(g + kg[t]);
        vr[t] = *(const s16x8*)(gv + (tid + t * 128) * 8);
      }
    }
    const short* kb = Klds[c & 1];
    const short* vb = Vlds[c & 1];
    s16x8 kf[6];
#pragma unroll
    for (int f = 0; f < 6; ++f)
      kf[f] = *(const s16x8*)&kb[(f * 64 + lane) * 8];
    f32x4 sT[3];
#pragma unroll
    for (int h = 0; h < 3; ++h) {
      sT[h] = __builtin_amdgcn_mfma_f32_16x16x32_bf16(kf[h * 2], qf[h][0], zz, 0, 0, 0);
      sT[h] = __builtin_amdgcn_mfma_f32_16x16x32_bf16(kf[h * 2 + 1], qf[h][1], sT[h], 0, 0, 0);
    }
    float p0[4], p1[4], p2[4];
#pragma unroll
    for (int r = 0; r < 4; ++r) {
      float s0 = sT[0][r], s1 = sT[1][r], s2 = sT[2][r];
      float e0 = exp2f(pm[0] * s0 + pm[3] * s1 + pm[6] * s2);
      float e1 = exp2f(pm[1] * s0 + pm[4] * s1 + pm[7] * s2);
      float e2 = exp2f(pm[2] * s0 + pm[5] * s1 + pm[8] * s2);
      p0[r] = poli[0] * e0 + poli[3] * e1 + poli[6] * e2;
      p1[r] = poli[1] * e0 + poli[4] * e1 + poli[7] * e2;
      p2[r] = poli[2] * e0 + poli[5] * e1 + poli[8] * e2;
    }
#if HAVE_MFMA16
    s16x4 pa[3];
#pragma unroll
    for (int j = 0; j < 4; ++j) {
      pa[0][j] = (short)f2bf(p0[j]); pa[1][j] = (short)f2bf(p1[j]); pa[2][j] = (short)f2bf(p2[j]);
    }
    s16x4 vf[12];
#pragma unroll
    for (int hd = 0; hd < 12; ++hd)
      vf[hd] = *(const s16x4*)&vb[(hd * 64 + lane) * 4];
#pragma unroll
    for (int h = 0; h < 3; ++h)
#pragma unroll
      for (int dt = 0; dt < 4; ++dt)
        o[h][dt] = __builtin_amdgcn_mfma_f32_16x16x16bf16_1k(pa[h], vf[h * 4 + dt], o[h][dt], 0, 0, 0);
#else
    // fallback: 16x16x32 with upper-half-zero A; B rows k=0..15 only matter.
    union U8 { s16x4 h4[2]; s16x8 v; };
    s16x8 pa8[3];
#pragma unroll
    for (int h = 0; h < 3; ++h) {
      float* pp = (h == 0) ? p0 : (h == 1) ? p1 : p2;
      unsigned int P01 = ((unsigned int)f2bf(pp[1]) << 16) | f2bf(pp[0]);
      unsigned int P23 = ((unsigned int)f2bf(pp[3]) << 16) | f2bf(pp[2]);
      int sbase = (lr + 16 * (2 * lg)) & 63;
      union { unsigned int u[4]; s16x8 v; } u;
      u.u[0] = __shfl(P01, sbase);             u.u[1] = __shfl(P23, sbase);
      u.u[2] = __shfl(P01, (sbase + 16) & 63); u.u[3] = __shfl(P23, (sbase + 16) & 63);
      if (lg >= 2) { u.u[0] = 0; u.u[1] = 0; u.u[2] = 0; u.u[3] = 0; }
      pa8[h] = u.v;
    }
#pragma unroll
    for (int h = 0; h < 3; ++h)
#pragma unroll
      for (int dt = 0; dt < 4; ++dt) {
        int hd = h * 4 + dt;
        U8 vv;
        vv.h4[0] = *(const s16x4*)&vb[(hd * 64 + (lg & 1) * 32 + lr) * 4];
        vv.h4[1] = *(const s16x4*)&vb[(hd * 64 + (lg & 1) * 32 + 16 + lr) * 4];
        o[h][dt] = __builtin_amdgcn_mfma_f32_16x16x32_bf16(pa8[h], vv.v, o[h][dt], 0, 0, 0);
      }
#endif
    if (pf) {
      short* kd = Klds[(c + 1) & 1];
      short* vd = Vlds[(c + 1) & 1];
#pragma unroll
      for (int t = 0; t < 3; ++t) {
        *(s16x8*)&kd[(tid + t * 128) * 8] = kr[t];
        *(s16x8*)&vd[(tid + t * 128) * 8] = vr[t];
      }
    }
    __syncthreads();
  }

#pragma unroll
  for (int h = 0; h < 3; ++h)
#pragma unroll
    for (int dt = 0; dt < 4; ++dt)
#pragma unroll
      for (int r = 0; r < 4; ++r)
        Ob[((size_t)b * LQ + q0 + lg * 4 + r) * C_ + h * 64 + dt * 16 + lr] = (short)f2bf(o[h][dt][r]);
}

extern "C" void kernel_launch(void* const* d_in, const int* in_sizes, int n_in,
                              void* d_out, int out_size, void* d_ws, size_t ws_size,
                              hipStream_t stream) {
  (void)in_sizes; (void)n_in; (void)out_size; (void)ws_size;
  const float* inq  = (const float*)d_in[0];
  const float* inkv = (const float*)d_in[1];
  const float* q_dw = (const float*)d_in[2];
  const float* q_sc = (const float*)d_in[3];
  const float* q_bi = (const float*)d_in[4];
  const float* q_me = (const float*)d_in[5];
  const float* q_va = (const float*)d_in[6];
  const float* q_pw = (const float*)d_in[7];
  const float* k_dw = (const float*)d_in[8];
  const float* k_sc = (const float*)d_in[9];
  const float* k_bi = (const float*)d_in[10];
  const float* k_me = (const float*)d_in[11];
  const float* k_va = (const float*)d_in[12];
  const float* k_pw = (const float*)d_in[13];
  const float* v_dw = (const float*)d_in[14];
  const float* v_sc = (const float*)d_in[15];
  const float* v_bi = (const float*)d_in[16];
  const float* v_me = (const float*)d_in[17];
  const float* v_va = (const float*)d_in[18];
  const float* v_pw = (const float*)d_in[19];
  const float* preS  = (const float*)d_in[20];
  const float* postS = (const float*)d_in[21];
  const float* outk  = (const float*)d_in[22];

  short* ws = (short*)d_ws;
  short* qdwb = ws;                       // 8*3136*192
  short* kdwb = qdwb + 4816896;           // 8*784*192
  short* vdwb = kdwb + 1204224;           // 8*784*192
  short* Qb   = vdwb + 1204224;           // 8*3136*192
  short* Kb   = Qb   + 4816896;           // 8*784*192
  short* VTb  = Kb   + 1204224;           // 8*49*3072 lane-major tiled (slot 1228800)
  short* aout = VTb  + 1228800;           // 8*3136*192
  short* Wt   = aout + 4816896;           // 4*192*192
  short* WtQ = Wt, *WtK = Wt + 36864, *WtV = Wt + 73728, *WtO = Wt + 110592;

  prep_kernel<<<6456, 256, 0, stream>>>(
      inq, inkv,
      q_dw, q_sc, q_bi, q_me, q_va,
      k_dw, k_sc, k_bi, k_me, k_va,
      v_dw, v_sc, v_bi, v_me, v_va,
      q_pw, k_pw, v_pw, outk,
      qdwb, kdwb, vdwb, Wt);
  proj_gemm_kernel<<<588, 256, 0, stream>>>(qdwb, kdwb, vdwb, WtQ, WtK, WtV, Qb, Kb, VTb);
  attn_mfma_kernel<<<784, 128, 0, stream>>>(Qb, Kb, VTb, preS, postS, aout);
  out_gemm_kernel<<<392, 256, 0, stream>>>(aout, WtO, (float*)d_out);
}